// Round 17
// baseline (113.958 us; speedup 1.0000x reference)
//
#include <hip/hip_runtime.h>
#include <hip/hip_bf16.h>
#include <stdint.h>

// y[c,k] = sum_{a,b} E1[k,a] * Xc[c,a,b] * E2[k,b],  Xc = C*x, E = exp(i*angle*g)
//
// R17 = R16 resubmitted verbatim (R16's bench was an infra failure — no
// signal). Theory under test: R15's barrier-free loop with MFMA shape
// 16x16x32 -> 32x32x16: halves instruction count / dependency edges /
// waitcnt boundaries in the K-loop (64 instead of 128 MFMAs per wave) at
// identical matrix-pipe time and identical 64-reg accumulator. This is the
// only untested mechanism after 6 structural nulls at ~63-65us with no
// pipe >40% (dependency/issue-bound regime).
//  - A operand mapping: row = l&31, k = (l>>5)*8+e (extrapolated from the
//    verified 16x16 pattern row=l&15,k=(l>>4)*8+e used in R0-R15).
//  - C/D mapping (guide-verified m74/m101): col = lane&31,
//    row = (reg&3) + 8*(reg>>2) + 4*(lane>>5), reg 0..15.
//  - A image re-tiled: af load = 2 x 512B contiguous runs per wave.
//  - B panel 64 k-rows x 256 cols in LDS (32KB), chunk-XOR swizzled
//    (pos = (chunk&24) | ((chunk&7)^(krow&7))) -> structural-min ds_read.
//
// A content per (c,a): A_re row a     = [Re XcC[j] | -Im XcS[j]], j=1..128
//                      A_im row 256+a = [Im XcC[j] |  Re XcS[j]]
//   XcC[j]=Xc[128+j]+Xc[128-j], XcS[j]=Xc[128+j]-Xc[128-j] (j=1..127)
//   XcC[128]=Xc[b=0], XcS[128]=-Xc[b=0];  bias row = Xc[a,b=128] (g=0 term)

#define NKTOT 17408
#define NBLK 272    // ktiles of 64 k-values
#define NT 8        // K-tiles of 32 (K = 256 exactly)

typedef short bf16x8 __attribute__((ext_vector_type(8)));
typedef float f32x4 __attribute__((ext_vector_type(4)));
typedef float f32x16 __attribute__((ext_vector_type(16)));

__device__ __forceinline__ unsigned short f2bf(float f) {
  unsigned int u = __builtin_bit_cast(unsigned int, f);
  u += 0x7FFFu + ((u >> 16) & 1u);
  return (unsigned short)(u >> 16);
}
__device__ __forceinline__ unsigned int pk2bf(float lo, float hi) {
  return (unsigned int)f2bf(lo) | ((unsigned int)f2bf(hi) << 16);
}

// A image (per c: 131072 ushorts = 256KB):
//   idx = (tt*2+q)*8192 + h*4096 + m*8 + e
//   for logical row m (0..511), col jj (0..255):
//   tt=jj>>5, q=(jj>>4)&1, h=(jj>>3)&1, e=jj&7
// af load (wave, tile tt, kstep q, rowgroup rg): lane l reads
//   m = w*64 + rg*32 + (l&31), h = l>>5  -> 2 x 512B contiguous runs.
__device__ __forceinline__ size_t aidx(int c, int m, int jj) {
  int tt = jj >> 5, q = (jj >> 4) & 1, h = (jj >> 3) & 1;
  return (size_t)c * 131072 + (tt * 2 + q) * 8192 + h * 4096 + m * 8 + (jj & 7);
}

// A fold + bias only (B/E1 computed inside gemm).
__global__ __launch_bounds__(256) void pack_a(
    const float* __restrict__ input_r, const float* __restrict__ C_r,
    unsigned short* __restrict__ Apack, float* __restrict__ biastab)
{
  const int bx = blockIdx.x;           // 0..1023
  const int tid = threadIdx.x;
  const int p = bx * 2 + (tid >> 7);   // (c,a) pair index 0..2047
  const int a = p & 255;
  const int c = p >> 8;
  const int j = tid & 127;
  const size_t xbase = (size_t)a * 256;
  const size_t cbase = ((size_t)(c * 256 + a)) * 256;
  if (j == 0) {
    // bias (b=128, g=0) and the unpaired b=0 (g=-128) fold
    float xr = input_r[(xbase + 128) * 2], xi = input_r[(xbase + 128) * 2 + 1];
    float cr = C_r[(cbase + 128) * 2],     ci = C_r[(cbase + 128) * 2 + 1];
    biastab[c * 512 + a]       = cr * xr - ci * xi;   // Re Xc[a,128]
    biastab[c * 512 + 256 + a] = cr * xi + ci * xr;   // Im Xc[a,128]
    xr = input_r[xbase * 2]; xi = input_r[xbase * 2 + 1];
    cr = C_r[cbase * 2];     ci = C_r[cbase * 2 + 1];
    float reb = cr * xr - ci * xi, imb = cr * xi + ci * xr;   // Xc[a,0]
    Apack[aidx(c, a, 127)]       = f2bf(reb);    // Re XcC[128]
    Apack[aidx(c, a, 255)]       = f2bf(imb);    // -Im XcS[128] = +Im Xc0
    Apack[aidx(c, 256 + a, 127)] = f2bf(imb);    // Im XcC[128]
    Apack[aidx(c, 256 + a, 255)] = f2bf(-reb);   // Re XcS[128] = -Re Xc0
  } else {
    const int bp = 128 + j, bm = 128 - j;
    float xpr = input_r[(xbase + bp) * 2], xpi = input_r[(xbase + bp) * 2 + 1];
    float cpr = C_r[(cbase + bp) * 2],     cpi = C_r[(cbase + bp) * 2 + 1];
    float pr = cpr * xpr - cpi * xpi, pi = cpr * xpi + cpi * xpr;
    float xmr = input_r[(xbase + bm) * 2], xmi = input_r[(xbase + bm) * 2 + 1];
    float cmr = C_r[(cbase + bm) * 2],     cmi = C_r[(cbase + bm) * 2 + 1];
    float mrv = cmr * xmr - cmi * xmi, miv = cmr * xmi + cmi * xmr;
    Apack[aidx(c, a, j - 1)]         = f2bf(pr + mrv);   //  Re XcC[j]
    Apack[aidx(c, a, 127 + j)]       = f2bf(miv - pi);   // -Im XcS[j]
    Apack[aidx(c, 256 + a, j - 1)]   = f2bf(pi + miv);   //  Im XcC[j]
    Apack[aidx(c, 256 + a, 127 + j)] = f2bf(pr - mrv);   //  Re XcS[j]
  }
}

__global__ __launch_bounds__(512, 4) void gemm_fused(
    const unsigned short* __restrict__ Apack,
    const float* __restrict__ biastab,
    const float* __restrict__ angle,
    const float* __restrict__ wvec,
    float* __restrict__ out)
{
  __shared__ unsigned short Bs[64 * 256];  // 32 KB: the ENTIRE B panel
  __shared__ float scol[8][2][64];         // 4 KB  => 36 KB -> 2 blocks/CU

  // XCD-aware decode: bx%8 == ktile%8. 2176 = 34*64 -> bijective.
  const int bx = blockIdx.x;
  const int c = (bx >> 3) & 7;
  const int ktile = (bx >> 6) * 8 + (bx & 7);   // 0..271
  const int kt0 = ktile * 64;
  const int tid = threadIdx.x;
  const int w = tid >> 6;       // 0..7: owns logical rows w*64..+63
  const int l = tid & 63;
  const int l31 = l & 31;
  const int l5 = l >> 5;        // A/B k-half

  // Per-lane A base: af(tt,q,rg) at Alane + (tt*2+q)*8192 + rg*256
  const unsigned short* Alane = Apack + (size_t)c * 131072
      + l5 * 4096 + (size_t)(w * 64 + l31) * 8;

  // ---- Prologue: compute the ENTIRE B panel into LDS.
  // Thread (w,l): k-row = l, cols jj = w*32 + o (o=0..31).
  // Content col jj: jj<128 -> cos(t*(jj+1)) ; jj>=128 -> sin(t*(jj-127));
  // both = trig(t*((w&3)*32 + o + 1)). Chain z_{o+1} = z_o * e^{it}.
  // Swizzled store: chunk = jj>>3 = w*4+oc; pos = (chunk&24)|((chunk&7)^(l&7));
  // ushort idx = l*256 + pos*8.
  {
    const float t_reg = angle[(size_t)(kt0 + l) * 2 + 1];
    float2 et;
    __sincosf(t_reg, &et.y, &et.x);
    float zr, zi;
    __sincosf(t_reg * (float)((w & 3) * 32 + 1), &zi, &zr);
    const bool use_cos = (w < 4);
#pragma unroll
    for (int oc = 0; oc < 4; ++oc) {
      float v[8];
#pragma unroll
      for (int o8 = 0; o8 < 8; ++o8) {
        v[o8] = use_cos ? zr : zi;
        float nr = zr * et.x - zi * et.y;
        float ni = zr * et.y + zi * et.x;
        zr = nr; zi = ni;
      }
      uint4 pk;
      pk.x = pk2bf(v[0], v[1]);
      pk.y = pk2bf(v[2], v[3]);
      pk.z = pk2bf(v[4], v[5]);
      pk.w = pk2bf(v[6], v[7]);
      const int chunk = w * 4 + oc;
      const int pos = (chunk & 24) | ((chunk & 7) ^ (l & 7));
      *(uint4*)&Bs[l * 256 + pos * 8] = pk;
    }
  }

  f32x16 acc[2][2];   // [rowgroup rg][colgroup cg]
  // acc init = bias (folded cos-col-0 rank-1 term; k-independent).
  // C/D row = w*64 + rg*32 + 4*l5 + (reg&3) + 8*(reg>>2).
#pragma unroll
  for (int rg = 0; rg < 2; ++rg) {
#pragma unroll
    for (int q2 = 0; q2 < 4; ++q2) {
      f32x4 b4 = *(const f32x4*)(biastab + c * 512 + w * 64 + rg * 32
                                 + 4 * l5 + 8 * q2);
#pragma unroll
      for (int r2 = 0; r2 < 4; ++r2) {
        acc[rg][0][q2 * 4 + r2] = b4[r2];
        acc[rg][1][q2 * 4 + r2] = b4[r2];
      }
    }
  }
  __syncthreads();

  // ---- Barrier-free K-loop: 16 ksteps of K=16, 4 x 32x32x16 MFMA each.
  // bfr(cg, ks): lane reads B[krow = cg*32+l31][kcontr = ks*16 + l5*8 + e];
  // chunk = ks*2 + l5, pos = (chunk&24)|((chunk&7)^(l&7)).
#pragma unroll 2
  for (int tt = 0; tt < NT; ++tt) {
#pragma unroll
    for (int q = 0; q < 2; ++q) {
      const int ks = tt * 2 + q;
      bf16x8 af0 = *(const bf16x8*)(Alane + (size_t)ks * 8192);
      bf16x8 af1 = *(const bf16x8*)(Alane + (size_t)ks * 8192 + 256);
      const int chunk = ks * 2 + l5;
      const int pos8 = ((chunk & 24) | ((chunk & 7) ^ (l & 7))) * 8;
      bf16x8 bf0 = *(const bf16x8*)&Bs[l31 * 256 + pos8];
      bf16x8 bf1 = *(const bf16x8*)&Bs[(32 + l31) * 256 + pos8];
      acc[0][0] = __builtin_amdgcn_mfma_f32_32x32x16_bf16(af0, bf0, acc[0][0], 0, 0, 0);
      acc[0][1] = __builtin_amdgcn_mfma_f32_32x32x16_bf16(af0, bf1, acc[0][1], 0, 0, 0);
      acc[1][0] = __builtin_amdgcn_mfma_f32_32x32x16_bf16(af1, bf0, acc[1][0], 0, 0, 0);
      acc[1][1] = __builtin_amdgcn_mfma_f32_32x32x16_bf16(af1, bf1, acc[1][1], 0, 0, 0);
    }
  }

  // ---- Epilogue. Lane holds, per (rg,cg), 16 T values at col = cg*32+l31,
  // rows m = w*64 + rg*32 + 4*l5 + (reg&3) + 8*(reg>>2)  (w<4: Tr, a=m;
  // w>=4: Ti, a=m-256). Factored E1 sum:
  //   S = e^{i s a0} * sum_q2 e^{i 8 s q2} * (sum_r2 e^{i s r2} v[q2*4+r2])
  //   a0 = (w&3)*64 + rg*32 + 4*l5 - 128, s = angle[k,0].
#pragma unroll
  for (int cg = 0; cg < 2; ++cg) {
    const int col = cg * 32 + l31;
    const int k = kt0 + col;
    const float s = angle[(size_t)k * 2];
    float s1, c1, s8, c8;
    __sincosf(s, &s1, &c1);
    __sincosf(8.f * s, &s8, &c8);
    float c2 = c1 * c1 - s1 * s1, s2 = 2.f * c1 * s1;
    float c3 = c2 * c1 - s2 * s1, s3 = c2 * s1 + s2 * c1;
    float c16 = c8 * c8 - s8 * s8, s16 = 2.f * c8 * s8;
    float c24 = c16 * c8 - s16 * s8, s24 = s16 * c8 + c16 * s8;
    const float Yr[4] = {1.f, c8, c16, c24};
    const float Yi[4] = {0.f, s8, s16, s24};
    float sumr = 0.f, sumi = 0.f;
#pragma unroll
    for (int rg = 0; rg < 2; ++rg) {
      float Or = 0.f, Oi = 0.f;
#pragma unroll
      for (int q2 = 0; q2 < 4; ++q2) {
        float v0 = acc[rg][cg][q2 * 4 + 0], v1 = acc[rg][cg][q2 * 4 + 1];
        float v2 = acc[rg][cg][q2 * 4 + 2], v3 = acc[rg][cg][q2 * 4 + 3];
        float Ir = v0 + c1 * v1 + c2 * v2 + c3 * v3;
        float Ii = s1 * v1 + s2 * v2 + s3 * v3;
        Or += Yr[q2] * Ir - Yi[q2] * Ii;
        Oi += Yi[q2] * Ir + Yr[q2] * Ii;
      }
      const float a0f = (float)((w & 3) * 64 + rg * 32 + 4 * l5 - 128);
      float sb, cb;
      __sincosf(s * a0f, &sb, &cb);
      sumr += cb * Or - sb * Oi;
      sumi += sb * Or + cb * Oi;
    }
    sumr += __shfl_xor(sumr, 32, 64);   // add the other l5-half's rows
    sumi += __shfl_xor(sumi, 32, 64);
    if (l5 == 0) {
      scol[w][0][col] = sumr;
      scol[w][1][col] = sumi;
    }
  }
  __syncthreads();
  if (tid < 128) {
    const int col = tid >> 1;
    const int comp = tid & 1;
    const int k = kt0 + col;
    // Re = sum_{w<4} S_r(w) - sum_{w>=4} S_i(w)
    // Im = sum_{w<4} S_i(w) + sum_{w>=4} S_r(w)
    float re = scol[0][0][col] + scol[1][0][col] + scol[2][0][col] + scol[3][0][col]
             - scol[4][1][col] - scol[5][1][col] - scol[6][1][col] - scol[7][1][col];
    float im = scol[0][1][col] + scol[1][1][col] + scol[2][1][col] + scol[3][1][col]
             + scol[4][0][col] + scol[5][0][col] + scol[6][0][col] + scol[7][0][col];
    float val = comp ? im : re;
    out[((size_t)c * NKTOT + k) * 2 + comp] = val * wvec[k & 511];
  }
}

extern "C" void kernel_launch(void* const* d_in, const int* in_sizes, int n_in,
                              void* d_out, int out_size, void* d_ws, size_t ws_size,
                              hipStream_t stream) {
  const float* input_r = (const float*)d_in[0];  // (256,256,2)
  const float* C_r     = (const float*)d_in[1];  // (8,256,256,2)
  const float* wvec    = (const float*)d_in[2];  // (512,)
  const float* angle   = (const float*)d_in[3];  // (17408,2)
  float* out = (float*)d_out;                    // (8,17408,2)

  // workspace: Apack 2MB | biastab 16KB  => ~2.1MB
  unsigned short* Apack = (unsigned short*)d_ws;
  float* biastab = (float*)((char*)d_ws + (size_t)2097152);

  pack_a<<<1024, 256, 0, stream>>>(input_r, C_r, Apack, biastab);
  gemm_fused<<<8 * NBLK, 512, 0, stream>>>(Apack, biastab, angle, wvec, out);
}